// Round 12
// baseline (12099.680 us; speedup 1.0000x reference)
//
#include <hip/hip_runtime.h>
#include <math.h>

// ---------------- problem constants ----------------
#define NB 8
#define NMELS 80
#define TT 512
#define NFREQ 401
#define NFFT 800
#define HOPSZ 200
#define NROWS (NB*TT)          // 4096 frames
#define LY 103000              // untrimmed istft length
#define LOUTW 102200
#define PADW 400
#define NSPEC (NROWS*NFREQ)    // 1640448
#define GLITERS 30
#define SGDITERS 50
#define SGD_SCALE 0.003125f    // 2/(B*n_mels)
#define KCAT 832               // concatenated K: [part0 416 | part1 416]
#define KHALF 416
#define NCOLS 448              // padded output cols (7*64), valid [0,400]
#define MAXSPAN 24             // max mel-band width in bins (measured 21)
#define GLGRID 448             // persistent grid = 7 x 64 (<= 256 CUs x 2)
// scales: A x256, B1 x16 (/800 dropped), lo parts x2048
#define WSQ_SCALE 3276800.0f   // 800*16*256
#define LO_INV 4.8828125e-4f   // 2^-11

#define TWO_PI_D 6.283185307179586476925286766559

typedef _Float16 half8 __attribute__((ext_vector_type(8)));
typedef float f32x4 __attribute__((ext_vector_type(4)));

// ---------------- threefry2x32 (20 rounds) ----------------
__host__ __device__ inline void tf2x32(unsigned k0, unsigned k1,
                                       unsigned x0, unsigned x1,
                                       unsigned& o0, unsigned& o1) {
  unsigned ks0 = k0, ks1 = k1, ks2 = k0 ^ k1 ^ 0x1BD11BDAu;
  x0 += ks0; x1 += ks1;
#define TF_R(r) { x0 += x1; x1 = (x1 << (r)) | (x1 >> (32 - (r))); x1 ^= x0; }
  TF_R(13) TF_R(15) TF_R(26) TF_R(6)
  x0 += ks1; x1 += ks2 + 1u;
  TF_R(17) TF_R(29) TF_R(16) TF_R(24)
  x0 += ks2; x1 += ks0 + 2u;
  TF_R(13) TF_R(15) TF_R(26) TF_R(6)
  x0 += ks0; x1 += ks1 + 3u;
  TF_R(17) TF_R(29) TF_R(16) TF_R(24)
  x0 += ks1; x1 += ks2 + 4u;
  TF_R(13) TF_R(15) TF_R(26) TF_R(6)
  x0 += ks2; x1 += ks0 + 5u;
#undef TF_R
  o0 = x0; o1 = x1;
}

__device__ inline float u01(unsigned bits) {
  unsigned u = (bits >> 9) | 0x3f800000u;
  return __uint_as_float(u) - 1.0f;
}

__device__ inline int ang_map(int g) {
  int b = g / (NFREQ * TT);
  int r = g - b * (NFREQ * TT);
  int f = r / TT;
  int t = r - f * TT;
  return (b * TT + t) * NFREQ + f;
}

__global__ void k_rand_spec(unsigned ka, unsigned kb, float* __restrict__ spec) {
  int i = blockIdx.x * blockDim.x + threadIdx.x;
  if (i >= NSPEC) return;
  unsigned o0, o1; tf2x32(ka, kb, 0u, (unsigned)i, o0, o1);
  spec[i] = u01(o0 ^ o1);    // partitionable 32-bit fold
}

__global__ void k_rand_ang(unsigned kra, unsigned krb, unsigned kia, unsigned kib,
                           float* __restrict__ ar, float* __restrict__ ai) {
  int g = blockIdx.x * blockDim.x + threadIdx.x;
  if (g >= NSPEC) return;
  int d = ang_map(g);
  unsigned o0, o1;
  tf2x32(kra, krb, 0u, (unsigned)g, o0, o1); ar[d] = u01(o0 ^ o1);
  tf2x32(kia, kib, 0u, (unsigned)g, o0, o1); ai[d] = u01(o0 ^ o1);
}

// ---------------- mel filterbank ----------------
__device__ inline double mel2hz_d(double mel) {
  return 700.0 * (pow(10.0, mel / 2595.0) - 1.0);
}

__global__ void k_fb(float* __restrict__ fbT, int* __restrict__ fm0,
                     float* __restrict__ fw0, float* __restrict__ fw1) {
  int f = blockIdx.x * blockDim.x + threadIdx.x;
  if (f >= NFREQ) return;
  const double freq = 10.0 * (double)f;
  const double melmax = 2595.0 * log10(1.0 + 4000.0 / 700.0);
  const double step = melmax / 81.0;
  int first = -1; float w0v = 0.f, w1v = 0.f;
  double p0 = 0.0;
  double p1 = mel2hz_d(step);
  for (int m = 0; m < NMELS; ++m) {
    double m2 = (m + 2 == 81) ? melmax : (double)(m + 2) * step;
    double p2 = mel2hz_d(m2);
    double down = (freq - p0) / (p1 - p0);
    double up   = (p2 - freq) / (p2 - p1);
    double v = down < up ? down : up;
    if (v < 0.0) v = 0.0;
    float vf = (float)v;
    fbT[m * NFREQ + f] = vf;
    if (vf > 0.f) {
      if (first < 0) { first = m; w0v = vf; }
      else if (m == first + 1) { w1v = vf; }
    }
    p0 = p1; p1 = p2;
  }
  fm0[f] = first < 0 ? 0 : first;
  fw0[f] = first < 0 ? 0.f : w0v;
  fw1[f] = w1v;
}

__global__ void k_ranges(const float* __restrict__ fbT, int* __restrict__ mlo,
                         int* __restrict__ mhi) {
  int m = threadIdx.x;
  if (m >= NMELS) return;
  int lo = NFREQ, hi = 0;
  for (int f = 0; f < NFREQ; ++f)
    if (fbT[m * NFREQ + f] > 0.f) { if (lo == NFREQ) lo = f; hi = f + 1; }
  mlo[m] = lo; mhi[m] = hi < lo ? lo : hi;
}

// ---------------- window + OLA weight (pre-scaled) + reciprocal ----------------
__device__ inline double hann_d(int i) {
  return 0.5 - 0.5 * cos(TWO_PI_D * (double)i / 800.0);
}

__global__ void k_wsq(float* __restrict__ wsqs, float* __restrict__ wsinv,
                      float* __restrict__ win) {
  int j = blockIdx.x * blockDim.x + threadIdx.x;
  if (j >= LY) return;
  if (j < NFFT) win[j] = (float)hann_d(j);
  int t1 = j / HOPSZ; if (t1 > TT - 1) t1 = TT - 1;
  int t0 = (j - (NFFT - HOPSZ)) / HOPSZ; if (t0 < 0) t0 = 0;
  float s = 0.f;
  for (int t = t0; t <= t1; ++t) {
    float w = (float)hann_d(j - t * HOPSZ);
    s += w * w;
  }
  s = fmaxf(s, 1e-11f);
  wsqs[j] = WSQ_SCALE * s;
  wsinv[j] = (float)(1.0 / ((double)WSQ_SCALE * (double)s));  // single rounding
}

// ---------------- symmetric f16-split DFT tables ----------------
__global__ void k_tabs1(_Float16* __restrict__ Bh, _Float16* __restrict__ Bl) {
  int idx = blockIdx.x * blockDim.x + threadIdx.x;
  if (idx >= NCOLS * KCAT) return;
  int n = idx / KCAT, kk = idx - n * KCAT;
  double v = 0.0;
  if (n <= 400) {
    if (kk < KHALF) {
      int k = kk;
      if (k <= 400) {
        double ak = (k == 0 || k == 400) ? 1.0 : 2.0;
        int ph = (k * n) % NFFT;
        v = 16.0 * ak * cos((double)ph * (TWO_PI_D / 800.0));
      }
    } else {
      int k = kk - KHALF;
      if (k <= 400) {
        int ph = (k * n) % NFFT;
        v = -32.0 * sin((double)ph * (TWO_PI_D / 800.0));
      }
    }
  }
  float vf = (float)v;
  _Float16 h = (_Float16)vf;
  Bh[idx] = h;
  Bl[idx] = (_Float16)((vf - (float)h) * 2048.0f);
}

__global__ void k_tabs2(_Float16* __restrict__ Bh, _Float16* __restrict__ Bl) {
  int idx = blockIdx.x * blockDim.x + threadIdx.x;
  if (idx >= NCOLS * KCAT) return;
  int kf = idx / KCAT, kk = idx - kf * KCAT;
  double v = 0.0;
  if (kf <= 400) {
    if (kk < KHALF) {
      int nt = kk;
      if (nt <= 400) {
        int ph = (kf * nt) % NFFT;
        v = cos((double)ph * (TWO_PI_D / 800.0));
      }
    } else {
      int nt = kk - KHALF;
      if (nt <= 400) {
        int ph = (kf * nt) % NFFT;
        v = -sin((double)ph * (TWO_PI_D / 800.0));
      }
    }
  }
  float vf = (float)v;
  _Float16 h = (_Float16)vf;
  Bh[idx] = h;
  Bl[idx] = (_Float16)((vf - (float)h) * 2048.0f);
}

// ---------------- InverseMelScale: register-resident SGD, 1 wave per row --------
__global__ __launch_bounds__(64) void k_sgd(
    const float* __restrict__ spec0, const float* __restrict__ xmel,
    const float* __restrict__ fbT, const int* __restrict__ mlo,
    const int* __restrict__ mhi, const int* __restrict__ fm0,
    const float* __restrict__ fw0, const float* __restrict__ fw1,
    float* __restrict__ mag) {
  __shared__ float s_spec[NFREQ], s_diff[NMELS];
  const int row = blockIdx.x;
  const int b = row / TT, t = row - b * TT;
  const int tid = threadIdx.x;

  float spec[7], vel[7];
  int qm0[7], qm1[7];
  float qw0[7], qw1[7];
#pragma unroll
  for (int q = 0; q < 7; ++q) {
    int f = tid + 64 * q;
    bool v = f < NFREQ;
    float sv = v ? spec0[row * NFREQ + f] : 0.f;
    spec[q] = sv; vel[q] = 0.f;
    if (v) s_spec[f] = sv;
    int m0 = v ? fm0[f] : 0;
    int m1 = m0 + 1; if (m1 > NMELS - 1) m1 = NMELS - 1;
    qm0[q] = m0; qm1[q] = m1;
    qw0[q] = v ? fw0[f] : 0.f;
    qw1[q] = v ? fw1[f] : 0.f;
  }

  const int mA = tid;
  const int mB = tid + 64;
  const bool hasB = mB < NMELS;
  float melA = xmel[(b * NMELS + mA) * TT + t];
  float melB = hasB ? xmel[(b * NMELS + mB) * TT + t] : 0.f;
  int loA = mlo[mA];
  int hiA = mhi[mA];
  int loB = hasB ? mlo[mB] : 0;
  int hiB = hasB ? mhi[mB] : 0;
  float fbA[MAXSPAN], fbB[MAXSPAN];
#pragma unroll
  for (int i = 0; i < MAXSPAN; ++i) {
    fbA[i] = (loA + i < hiA) ? fbT[mA * NFREQ + loA + i] : 0.f;
    fbB[i] = (hasB && loB + i < hiB) ? fbT[mB * NFREQ + loB + i] : 0.f;
  }
  __syncthreads();

  for (int it = 0; it < SGDITERS; ++it) {
    float accA = 0.f, accB = 0.f;
#pragma unroll
    for (int i = 0; i < MAXSPAN; ++i) {
      int fA = loA + i; if (fA > 400) fA = 400;
      int fB = loB + i; if (fB > 400) fB = 400;
      accA = fmaf(fbA[i], s_spec[fA], accA);
      accB = fmaf(fbB[i], s_spec[fB], accB);
    }
    s_diff[mA] = melA - accA;
    if (hasB) s_diff[mB] = melB - accB;
    __syncthreads();
#pragma unroll
    for (int q = 0; q < 7; ++q) {
      int f = tid + 64 * q;
      if (f < NFREQ) {
        float d = s_diff[qm0[q]] * qw0[q] + s_diff[qm1[q]] * qw1[q];
        float g = -SGD_SCALE * d;
        float v = 0.9f * vel[q] + g;
        vel[q] = v;
        float sp = spec[q] - 0.1f * v;
        sp = sp > 0.f ? sp : 0.f;
        spec[q] = sp;
        s_spec[f] = sp;
      }
    }
    __syncthreads();
  }
#pragma unroll
  for (int q = 0; q < 7; ++q) {
    int f = tid + 64 * q;
    if (f < NFREQ) mag[row * NFREQ + f] = sqrtf(spec[q]);
  }
}

// ---------------- A1 prep (iteration 0; layout [Re@0|Im@416], pads zeroed) --------
__global__ void k_prep1(const float* __restrict__ mag, const float* __restrict__ ar,
                        const float* __restrict__ ai,
                        _Float16* __restrict__ Ah, _Float16* __restrict__ Al) {
  int kk = blockIdx.x * 256 + threadIdx.x;
  if (kk >= KCAT) return;
  int row = blockIdx.y;
  float v = 0.f;
  if (kk < KHALF) {
    int k = kk;
    if (k <= 400) { int gi = row * NFREQ + k; v = mag[gi] * ar[gi] * 256.0f; }
  } else {
    int k = kk - KHALF;
    if (k <= 400) { int gi = row * NFREQ + k; v = mag[gi] * ai[gi] * 256.0f; }
  }
  _Float16 h = (_Float16)v;
  size_t o = (size_t)row * KCAT + kk;
  Ah[o] = h;
  Al[o] = (_Float16)((v - (float)h) * 2048.0f);
}

// ---------------- shared GEMM macros (double-buffered, 1 barrier/chunk) ----------
#define GEMM_STAGE(BUF)                                                         \
    *(uint4*)&As_h[BUF][sr * 40 + sk] = pa_h;                                   \
    *(uint4*)&As_l[BUF][sr * 40 + sk] = pa_l;                                   \
    *(uint4*)&Bs_h[BUF][sr * 40 + sk] = pb_h;                                   \
    *(uint4*)&Bs_l[BUF][sr * 40 + sk] = pb_l;

#define GEMM_COMPUTE(BUF, A0, A1v)                                              \
  {                                                                             \
    half8 a_h[2], a_l[2];                                                       \
    _Pragma("unroll")                                                           \
    for (int i = 0; i < 2; ++i) {                                               \
      int m = wm * 32 + i * 16 + lm;                                            \
      a_h[i] = *(const half8*)&As_h[BUF][m * 40 + qd * 8];                      \
      a_l[i] = *(const half8*)&As_l[BUF][m * 40 + qd * 8];                      \
    }                                                                           \
    _Pragma("unroll")                                                           \
    for (int j = 0; j < 2; ++j) {                                               \
      int n = wn * 32 + j * 16 + lm;                                            \
      half8 b_h = *(const half8*)&Bs_h[BUF][n * 40 + qd * 8];                   \
      half8 b_l = *(const half8*)&Bs_l[BUF][n * 40 + qd * 8];                   \
      _Pragma("unroll")                                                         \
      for (int i = 0; i < 2; ++i) {                                             \
        A0[i][j]  = __builtin_amdgcn_mfma_f32_16x16x32_f16(a_h[i], b_h, A0[i][j], 0, 0, 0);  \
        A1v[i][j] = __builtin_amdgcn_mfma_f32_16x16x32_f16(a_h[i], b_l, A1v[i][j], 0, 0, 0); \
        A1v[i][j] = __builtin_amdgcn_mfma_f32_16x16x32_f16(a_l[i], b_h, A1v[i][j], 0, 0, 0); \
      }                                                                         \
    }                                                                           \
  }

// K=832, 26 chunks of 32; chunks 0..12 -> (ac0,ac1), 13..25 -> (as0,as1).
#define GEMM_LOOP                                                               \
  uint4 pa_h = *(const uint4*)&Ah[abase];                                       \
  uint4 pa_l = *(const uint4*)&Al[abase];                                       \
  uint4 pb_h = *(const uint4*)&Bh[bbase];                                       \
  uint4 pb_l = *(const uint4*)&Bl[bbase];                                       \
  GEMM_STAGE(0)                                                                 \
  _Pragma("unroll 2")                                                           \
  for (int c = 0; c < 26; ++c) {                                                \
    __syncthreads();                                                            \
    if (c < 25) {                                                               \
      int off = (c + 1) * 32;                                                   \
      pa_h = *(const uint4*)&Ah[abase + off];                                   \
      pa_l = *(const uint4*)&Al[abase + off];                                   \
      pb_h = *(const uint4*)&Bh[bbase + off];                                   \
      pb_l = *(const uint4*)&Bl[bbase + off];                                   \
    }                                                                           \
    const int bf = c & 1;                                                       \
    if (c < 13) { GEMM_COMPUTE(bf, ac0, ac1) } else { GEMM_COMPUTE(bf, as0, as1) } \
    if (c < 25) { GEMM_STAGE(bf ^ 1) }                                          \
  }

// ---------------- OLA sample helper ----------------
__device__ inline float sample_y(const float* __restrict__ fb_,
                                 const float* __restrict__ wsinv, int j) {
  int jm = (j < PADW) ? (NFFT - j) : ((j < PADW + LOUTW) ? j : (205198 - j));
  int t1 = jm / HOPSZ; if (t1 > TT - 1) t1 = TT - 1;
  int t0 = (jm - (NFFT - HOPSZ)) / HOPSZ; if (t0 < 0) t0 = 0;
  float s = 0.f;
  for (int t = t0; t <= t1; ++t) s += fb_[t * NFFT + (jm - t * HOPSZ)];
  return s * wsinv[jm];
}

// ---------------- software grid barrier (agent-scope, capture-safe) ----------
// bar[0]=arrive count, bar[1]=generation. Bounded spin: never hangs the queue.
__device__ inline void gbar(unsigned* __restrict__ bar) {
  __syncthreads();                       // drains vmcnt for all waves
  if (threadIdx.x == 0) {
    __threadfence();                     // release: L2 writeback (agent scope)
    unsigned gen = __hip_atomic_load(&bar[1], __ATOMIC_RELAXED, __HIP_MEMORY_SCOPE_AGENT);
    unsigned arrived = __hip_atomic_fetch_add(&bar[0], 1u, __ATOMIC_ACQ_REL, __HIP_MEMORY_SCOPE_AGENT);
    if (arrived == GLGRID - 1) {
      __hip_atomic_store(&bar[0], 0u, __ATOMIC_RELAXED, __HIP_MEMORY_SCOPE_AGENT);
      __hip_atomic_store(&bar[1], gen + 1u, __ATOMIC_RELEASE, __HIP_MEMORY_SCOPE_AGENT);
    } else {
      long cap = 0;
      while (__hip_atomic_load(&bar[1], __ATOMIC_ACQUIRE, __HIP_MEMORY_SCOPE_AGENT) == gen) {
        __builtin_amdgcn_s_sleep(2);
        if (++cap > (1L << 21)) break;   // ~100 ms failsafe: wrong > hung
      }
    }
    __threadfence();                     // acquire: invalidate stale L1/L2
  }
  __syncthreads();
}

__global__ void k_zbar(unsigned* __restrict__ bar) {
  if (threadIdx.x < 4) bar[threadIdx.x] = 0u;
}

// ---------------- persistent Griffin-Lim loop kernel (regular launch) ----------
// grid 448 = 7(col) x 64(row), 256 threads, LDS 40 KB, 2 blocks/CU guaranteed.
__global__ __launch_bounds__(256, 2) void k_gl(
    _Float16* __restrict__ A1h, _Float16* __restrict__ A1l,
    const _Float16* __restrict__ B1h, const _Float16* __restrict__ B1l,
    _Float16* __restrict__ A2h, _Float16* __restrict__ A2l,
    const _Float16* __restrict__ B2h, const _Float16* __restrict__ B2l,
    const float* __restrict__ win, const float* __restrict__ wsinv,
    const float* __restrict__ mag,
    float* __restrict__ tppr, float* __restrict__ tppi,
    float* __restrict__ frames, unsigned* __restrict__ bar, float beta) {
  __shared__ __align__(16) _Float16 As_h[2][64 * 40], As_l[2][64 * 40];
  __shared__ __align__(16) _Float16 Bs_h[2][64 * 40], Bs_l[2][64 * 40];
  const int t = threadIdx.x;
  const int bid = blockIdx.x;
  const int bx = bid % 7, by = bid / 7;
  const int row0 = by * 64;
  const int col0 = bx * 64;
  const int sr = t >> 2, sk = (t & 3) * 8;
  const int lane = t & 63, wv = t >> 6;
  const int wm = wv & 1, wn = wv >> 1;
  const int lm = lane & 15, qd = lane >> 4;

  auto mm1_phase = [&]() {
    const _Float16* Ah = A1h; const _Float16* Al = A1l;
    const _Float16* Bh = B1h; const _Float16* Bl = B1l;
    f32x4 ac0[2][2] = {}, ac1[2][2] = {}, as0[2][2] = {}, as1[2][2] = {};
    const size_t abase = (size_t)(row0 + sr) * KCAT + sk;
    const size_t bbase = (size_t)(col0 + sr) * KCAT + sk;
    GEMM_LOOP
#pragma unroll
    for (int j = 0; j < 2; ++j) {
      int col = col0 + wn * 32 + j * 16 + lm;
      if (col <= 400) {
        float wA = win[col];
        bool mir = (col >= 1 && col <= 399);
        float wB = mir ? win[800 - col] : 0.f;
#pragma unroll
        for (int i = 0; i < 2; ++i)
#pragma unroll
          for (int r = 0; r < 4; ++r) {
            int row = row0 + wm * 32 + i * 16 + qd * 4 + r;
            float Cv = ac0[i][j][r] + ac1[i][j][r] * LO_INV;
            float Sv = as0[i][j][r] + as1[i][j][r] * LO_INV;
            frames[(size_t)row * NFFT + col] = (Cv + Sv) * wA;
            if (mir) frames[(size_t)row * NFFT + (800 - col)] = (Cv - Sv) * wB;
          }
      }
    }
  };

  auto olaprep_phase = [&]() {
    for (int idx = bid * 256 + t; idx < NROWS * KHALF; idx += GLGRID * 256) {
      int row = idx / KHALF, n = idx - row * KHALF;
      size_t ab = (size_t)row * KCAT;
      if (n > 400) {                                  // K pads
        A2h[ab + n] = (_Float16)0.f; A2l[ab + n] = (_Float16)0.f;
        A2h[ab + KHALF + n] = (_Float16)0.f; A2l[ab + KHALF + n] = (_Float16)0.f;
        continue;
      }
      int b = row >> 9, tt = row & 511;
      const float* fb_ = frames + (size_t)b * TT * NFFT;
      int start = tt * HOPSZ;
      float x1 = sample_y(fb_, wsinv, start + n) * win[n] * 256.0f;
      float x2 = 0.f;
      // mirror only n in [1,399]: n==400 self-maps; n==0 mirror OOB
      if (n >= 1 && n <= 399)
        x2 = sample_y(fb_, wsinv, start + 800 - n) * win[800 - n] * 256.0f;
      float E = x1 + x2, O = x1 - x2;
      _Float16 Eh = (_Float16)E;
      A2h[ab + n] = Eh;
      A2l[ab + n] = (_Float16)((E - (float)Eh) * 2048.0f);
      _Float16 Oh = (_Float16)O;
      A2h[ab + KHALF + n] = Oh;
      A2l[ab + KHALF + n] = (_Float16)((O - (float)Oh) * 2048.0f);
    }
  };

  auto mm2_phase = [&]() {
    const _Float16* Ah = A2h; const _Float16* Al = A2l;
    const _Float16* Bh = B2h; const _Float16* Bl = B2l;
    f32x4 ac0[2][2] = {}, ac1[2][2] = {}, as0[2][2] = {}, as1[2][2] = {};
    const size_t abase = (size_t)(row0 + sr) * KCAT + sk;
    const size_t bbase = (size_t)(col0 + sr) * KCAT + sk;
    GEMM_LOOP
#pragma unroll
    for (int j = 0; j < 2; ++j) {
      int col = col0 + wn * 32 + j * 16 + lm;
      if (col <= 400) {
#pragma unroll
        for (int i = 0; i < 2; ++i)
#pragma unroll
          for (int r = 0; r < 4; ++r) {
            int row = row0 + wm * 32 + i * 16 + qd * 4 + r;
            int idx = row * NFREQ + col;
            float rr = ac0[i][j][r] + ac1[i][j][r] * LO_INV;   // Re (x256)
            float ri = as0[i][j][r] + as1[i][j][r] * LO_INV;   // Im
            float nr = rr - beta * tppr[idx];
            float ni = ri - beta * tppi[idx];
            tppr[idx] = rr; tppi[idx] = ri;
            float den = sqrtf(nr * nr + ni * ni) + 1e-16f;
            float arv = nr / den, aiv = ni / den;
            float mg = mag[idx] * 256.0f;
            size_t ab = (size_t)row * KCAT;
            float v1 = mg * arv;
            _Float16 h1 = (_Float16)v1;
            A1h[ab + col] = h1;
            A1l[ab + col] = (_Float16)((v1 - (float)h1) * 2048.0f);
            float v2 = mg * aiv;
            _Float16 h2 = (_Float16)v2;
            A1h[ab + KHALF + col] = h2;
            A1l[ab + KHALF + col] = (_Float16)((v2 - (float)h2) * 2048.0f);
          }
      }
    }
  };

  for (int it = 0; it < GLITERS; ++it) {
    mm1_phase();
    gbar(bar);
    olaprep_phase();
    gbar(bar);
    mm2_phase();
    gbar(bar);
  }
  mm1_phase();   // final istft frames with final angles
}

// ---------------- final overlap-add (full y, once; exact divide) ----------------
__global__ void k_ola(const float* __restrict__ frames, const float* __restrict__ wsqs,
                      float* __restrict__ y) {
  int idx = blockIdx.x * blockDim.x + threadIdx.x;
  if (idx >= NB * LY) return;
  int b = idx / LY, j = idx - b * LY;
  int t1 = j / HOPSZ; if (t1 > TT - 1) t1 = TT - 1;
  int t0 = (j - (NFFT - HOPSZ)) / HOPSZ; if (t0 < 0) t0 = 0;
  const float* fb_ = frames + (size_t)b * TT * NFFT;
  float s = 0.f;
  for (int t = t0; t <= t1; ++t) s += fb_[t * NFFT + (j - t * HOPSZ)];
  y[idx] = s / wsqs[j];
}

// ---------------- epilogue: peak-normalize ----------------
__global__ void k_absmax(const float* __restrict__ y, float* __restrict__ peak) {
  __shared__ float red[256];
  int b = blockIdx.x;
  const float* yb = y + (size_t)b * LY + PADW;
  float mx = 0.f;
  for (int j = threadIdx.x; j < LOUTW; j += 256) mx = fmaxf(mx, fabsf(yb[j]));
  red[threadIdx.x] = mx;
  __syncthreads();
  for (int s2 = 128; s2 > 0; s2 >>= 1) {
    if (threadIdx.x < s2) red[threadIdx.x] = fmaxf(red[threadIdx.x], red[threadIdx.x + s2]);
    __syncthreads();
  }
  if (threadIdx.x == 0) peak[b] = red[0];
}

__global__ void k_scale(const float* __restrict__ y, const float* __restrict__ peak,
                        float* __restrict__ out, float target) {
  int idx = blockIdx.x * blockDim.x + threadIdx.x;
  if (idx >= NB * LOUTW) return;
  int b = idx / LOUTW, j = idx - b * LOUTW;
  out[idx] = y[(size_t)b * LY + PADW + j] * (target / peak[b]);
}

__global__ void k_zero2(float* __restrict__ a, float* __restrict__ b, int n) {
  int i = blockIdx.x * blockDim.x + threadIdx.x;
  if (i < n) { a[i] = 0.f; b[i] = 0.f; }
}

// ---------------- host ----------------
extern "C" void kernel_launch(void* const* d_in, const int* in_sizes, int n_in,
                              void* d_out, int out_size, void* d_ws, size_t ws_size,
                              hipStream_t stream) {
  const float* xmel = (const float*)d_in[0];   // (8, 80, 512) f32
  float* out = (float*)d_out;                  // (8, 1, 102200) f32

  char* p = (char*)d_ws;
  auto alloc = [&](size_t nbytes) -> void* {
    void* r = (void*)p;
    p += (nbytes + 255) & ~(size_t)255;
    return r;
  };
  float* mag  = (float*)alloc((size_t)NSPEC * 4);
  float* ar   = (float*)alloc((size_t)NSPEC * 4);
  float* ai   = (float*)alloc((size_t)NSPEC * 4);
  float* tpr  = (float*)alloc((size_t)NSPEC * 4);
  float* tpi  = (float*)alloc((size_t)NSPEC * 4);
  float* y    = (float*)alloc((size_t)NB * LY * 4);
  float* win  = (float*)alloc(NFFT * 4);
  float* wsqs = (float*)alloc((size_t)LY * 4);
  float* wsinv= (float*)alloc((size_t)LY * 4);
  float* fbT  = (float*)alloc((size_t)NMELS * NFREQ * 4);
  float* fw0  = (float*)alloc(NFREQ * 4);
  float* fw1  = (float*)alloc(NFREQ * 4);
  float* peak = (float*)alloc(NB * 4);
  int* fm0    = (int*)alloc(NFREQ * 4);
  int* mlo    = (int*)alloc(NMELS * 4);
  int* mhi    = (int*)alloc(NMELS * 4);
  unsigned* bar = (unsigned*)alloc(16);
  float* frames = (float*)alloc((size_t)NROWS * NFFT * 4);
  float* spec0 = frames;  // alias: consumed by k_sgd before frames written
  _Float16* A1h = (_Float16*)alloc((size_t)NROWS * KCAT * 2);
  _Float16* A1l = (_Float16*)alloc((size_t)NROWS * KCAT * 2);
  _Float16* A2h = (_Float16*)alloc((size_t)NROWS * KCAT * 2);
  _Float16* A2l = (_Float16*)alloc((size_t)NROWS * KCAT * 2);
  _Float16* B1h = (_Float16*)alloc((size_t)NCOLS * KCAT * 2);
  _Float16* B1l = (_Float16*)alloc((size_t)NCOLS * KCAT * 2);
  _Float16* B2h = (_Float16*)alloc((size_t)NCOLS * KCAT * 2);
  _Float16* B2l = (_Float16*)alloc((size_t)NCOLS * KCAT * 2);

  if ((size_t)(p - (char*)d_ws) > ws_size) return;  // insufficient scratch

  // derived threefry keys (jax partitionable split)
  unsigned k1a, k1b, k2a, k2b, kra, krb, kia, kib;
  {
    unsigned o0, o1;
    tf2x32(0u, 1u, 0u, 0u, o0, o1); k1a = o0; k1b = o1;
    tf2x32(0u, 1u, 0u, 1u, o0, o1); k2a = o0; k2b = o1;
    tf2x32(k2a, k2b, 0u, 0u, o0, o1); kra = o0; krb = o1;
    tf2x32(k2a, k2b, 0u, 1u, o0, o1); kia = o0; kib = o1;
  }

  // init
  k_fb<<<2, 256, 0, stream>>>(fbT, fm0, fw0, fw1);
  k_ranges<<<1, 128, 0, stream>>>(fbT, mlo, mhi);
  k_wsq<<<(LY + 255) / 256, 256, 0, stream>>>(wsqs, wsinv, win);
  k_tabs1<<<(NCOLS * KCAT + 255) / 256, 256, 0, stream>>>(B1h, B1l);
  k_tabs2<<<(NCOLS * KCAT + 255) / 256, 256, 0, stream>>>(B2h, B2l);
  k_zero2<<<(NSPEC + 255) / 256, 256, 0, stream>>>(tpr, tpi, NSPEC);
  k_zbar<<<1, 64, 0, stream>>>(bar);
  k_rand_spec<<<(NSPEC + 255) / 256, 256, 0, stream>>>(k1a, k1b, spec0);
  k_rand_ang<<<(NSPEC + 255) / 256, 256, 0, stream>>>(kra, krb, kia, kib, ar, ai);

  // InverseMelScale (1 wave per (b,t) row, register-resident)
  k_sgd<<<NROWS, 64, 0, stream>>>(spec0, xmel, fbT, mlo, mhi, fm0, fw0, fw1, mag);

  // iteration-0 A1 (layout [Re@0|Im@416], pads zeroed once)
  k_prep1<<<dim3(4, NROWS), 256, 0, stream>>>(mag, ar, ai, A1h, A1l);

  // Griffin-Lim: persistent kernel (regular launch, software grid barrier)
  const float beta = (float)(0.99 / 1.99);
  k_gl<<<GLGRID, 256, 0, stream>>>(A1h, A1l, B1h, B1l, A2h, A2l, B2h, B2l,
                                   win, wsinv, mag, tpr, tpi, frames, bar, beta);

  // final OLA + normalize
  k_ola<<<(NB * LY + 255) / 256, 256, 0, stream>>>(frames, wsqs, y);
  k_absmax<<<NB, 256, 0, stream>>>(y, peak);
  const float target = (float)pow(10.0, -0.1 / 20.0);
  k_scale<<<(NB * LOUTW + 255) / 256, 256, 0, stream>>>(y, peak, out, target);
}

// Round 13
// 2509.542 us; speedup vs baseline: 4.8215x; 4.8215x over previous
//
#include <hip/hip_runtime.h>
#include <math.h>

// ---------------- problem constants ----------------
#define NB 8
#define NMELS 80
#define TT 512
#define NFREQ 401
#define NFFT 800
#define HOPSZ 200
#define NROWS (NB*TT)          // 4096 frames
#define LY 103000              // untrimmed istft length
#define LOUTW 102200
#define PADW 400
#define NSPEC (NROWS*NFREQ)    // 1640448
#define GLITERS 30
#define SGDITERS 50
#define SGD_SCALE 0.003125f    // 2/(B*n_mels)
#define KCAT 832               // concatenated K: [part0 416 | part1 416]
#define KHALF 416
#define NCOLS 448              // padded output cols (7*64), valid [0,400]
#define MAXSPAN 24             // max mel-band width in bins (measured 21)
// scales: A x256, B1 x16 (/800 dropped), lo parts x2048
#define WSQ_SCALE 3276800.0f   // 800*16*256
#define LO_INV 4.8828125e-4f   // 2^-11

#define TWO_PI_D 6.283185307179586476925286766559

typedef _Float16 half8 __attribute__((ext_vector_type(8)));
typedef float f32x4 __attribute__((ext_vector_type(4)));

// ---------------- threefry2x32 (20 rounds) ----------------
__host__ __device__ inline void tf2x32(unsigned k0, unsigned k1,
                                       unsigned x0, unsigned x1,
                                       unsigned& o0, unsigned& o1) {
  unsigned ks0 = k0, ks1 = k1, ks2 = k0 ^ k1 ^ 0x1BD11BDAu;
  x0 += ks0; x1 += ks1;
#define TF_R(r) { x0 += x1; x1 = (x1 << (r)) | (x1 >> (32 - (r))); x1 ^= x0; }
  TF_R(13) TF_R(15) TF_R(26) TF_R(6)
  x0 += ks1; x1 += ks2 + 1u;
  TF_R(17) TF_R(29) TF_R(16) TF_R(24)
  x0 += ks2; x1 += ks0 + 2u;
  TF_R(13) TF_R(15) TF_R(26) TF_R(6)
  x0 += ks0; x1 += ks1 + 3u;
  TF_R(17) TF_R(29) TF_R(16) TF_R(24)
  x0 += ks1; x1 += ks2 + 4u;
  TF_R(13) TF_R(15) TF_R(26) TF_R(6)
  x0 += ks2; x1 += ks0 + 5u;
#undef TF_R
  o0 = x0; o1 = x1;
}

__device__ inline float u01(unsigned bits) {
  unsigned u = (bits >> 9) | 0x3f800000u;
  return __uint_as_float(u) - 1.0f;
}

__device__ inline int ang_map(int g) {
  int b = g / (NFREQ * TT);
  int r = g - b * (NFREQ * TT);
  int f = r / TT;
  int t = r - f * TT;
  return (b * TT + t) * NFREQ + f;
}

__global__ void k_rand_spec(unsigned ka, unsigned kb, float* __restrict__ spec) {
  int i = blockIdx.x * blockDim.x + threadIdx.x;
  if (i >= NSPEC) return;
  unsigned o0, o1; tf2x32(ka, kb, 0u, (unsigned)i, o0, o1);
  spec[i] = u01(o0 ^ o1);    // partitionable 32-bit fold
}

__global__ void k_rand_ang(unsigned kra, unsigned krb, unsigned kia, unsigned kib,
                           float* __restrict__ ar, float* __restrict__ ai) {
  int g = blockIdx.x * blockDim.x + threadIdx.x;
  if (g >= NSPEC) return;
  int d = ang_map(g);
  unsigned o0, o1;
  tf2x32(kra, krb, 0u, (unsigned)g, o0, o1); ar[d] = u01(o0 ^ o1);
  tf2x32(kia, kib, 0u, (unsigned)g, o0, o1); ai[d] = u01(o0 ^ o1);
}

// ---------------- fp64 trig tables: ctab/stab[ph] = cos/sin(ph*2pi/800) -------
__global__ void k_trig(double* __restrict__ ctab, double* __restrict__ stab) {
  int i = blockIdx.x * 256 + threadIdx.x;
  if (i >= NFFT) return;
  double ang = (double)i * (TWO_PI_D / 800.0);
  ctab[i] = cos(ang);
  stab[i] = sin(ang);
}

// ---------------- mel filterbank ----------------
__device__ inline double mel2hz_d(double mel) {
  return 700.0 * (pow(10.0, mel / 2595.0) - 1.0);
}

__global__ void k_fb(float* __restrict__ fbT, int* __restrict__ fm0,
                     float* __restrict__ fw0, float* __restrict__ fw1) {
  int f = blockIdx.x * blockDim.x + threadIdx.x;
  if (f >= NFREQ) return;
  const double freq = 10.0 * (double)f;
  const double melmax = 2595.0 * log10(1.0 + 4000.0 / 700.0);
  const double step = melmax / 81.0;
  int first = -1; float w0v = 0.f, w1v = 0.f;
  double p0 = 0.0;
  double p1 = mel2hz_d(step);
  for (int m = 0; m < NMELS; ++m) {
    double m2 = (m + 2 == 81) ? melmax : (double)(m + 2) * step;
    double p2 = mel2hz_d(m2);
    double down = (freq - p0) / (p1 - p0);
    double up   = (p2 - freq) / (p2 - p1);
    double v = down < up ? down : up;
    if (v < 0.0) v = 0.0;
    float vf = (float)v;
    fbT[m * NFREQ + f] = vf;
    if (vf > 0.f) {
      if (first < 0) { first = m; w0v = vf; }
      else if (m == first + 1) { w1v = vf; }
    }
    p0 = p1; p1 = p2;
  }
  fm0[f] = first < 0 ? 0 : first;
  fw0[f] = first < 0 ? 0.f : w0v;
  fw1[f] = w1v;
}

__global__ void k_ranges(const float* __restrict__ fbT, int* __restrict__ mlo,
                         int* __restrict__ mhi) {
  int m = threadIdx.x;
  if (m >= NMELS) return;
  int lo = NFREQ, hi = 0;
  for (int f = 0; f < NFREQ; ++f)
    if (fbT[m * NFREQ + f] > 0.f) { if (lo == NFREQ) lo = f; hi = f + 1; }
  mlo[m] = lo; mhi[m] = hi < lo ? lo : hi;
}

// ---------------- window + OLA weight (pre-scaled) + reciprocal ----------------
// hann(i) = 0.5 - 0.5*cos(i*2pi/800) = 0.5 - 0.5*ctab[i]  (bit-identical)
__global__ void k_wsq(const double* __restrict__ ctab,
                      float* __restrict__ wsqs, float* __restrict__ wsinv,
                      float* __restrict__ win) {
  int j = blockIdx.x * blockDim.x + threadIdx.x;
  if (j >= LY) return;
  if (j < NFFT) win[j] = (float)(0.5 - 0.5 * ctab[j]);
  int t1 = j / HOPSZ; if (t1 > TT - 1) t1 = TT - 1;
  int t0 = (j - (NFFT - HOPSZ)) / HOPSZ; if (t0 < 0) t0 = 0;
  float s = 0.f;
  for (int t = t0; t <= t1; ++t) {
    float w = (float)(0.5 - 0.5 * ctab[j - t * HOPSZ]);
    s += w * w;
  }
  s = fmaxf(s, 1e-11f);
  wsqs[j] = WSQ_SCALE * s;
  wsinv[j] = (float)(1.0 / ((double)WSQ_SCALE * (double)s));  // single rounding
}

// ---------------- symmetric f16-split DFT tables ----------------
__global__ void k_tabs1(const double* __restrict__ ctab, const double* __restrict__ stab,
                        _Float16* __restrict__ Bh, _Float16* __restrict__ Bl) {
  int idx = blockIdx.x * blockDim.x + threadIdx.x;
  if (idx >= NCOLS * KCAT) return;
  int n = idx / KCAT, kk = idx - n * KCAT;
  double v = 0.0;
  if (n <= 400) {
    if (kk < KHALF) {
      int k = kk;
      if (k <= 400) {
        double ak = (k == 0 || k == 400) ? 1.0 : 2.0;
        int ph = (k * n) % NFFT;
        v = 16.0 * ak * ctab[ph];
      }
    } else {
      int k = kk - KHALF;
      if (k <= 400) {
        int ph = (k * n) % NFFT;
        v = -32.0 * stab[ph];
      }
    }
  }
  float vf = (float)v;
  _Float16 h = (_Float16)vf;
  Bh[idx] = h;
  Bl[idx] = (_Float16)((vf - (float)h) * 2048.0f);
}

__global__ void k_tabs2(const double* __restrict__ ctab, const double* __restrict__ stab,
                        _Float16* __restrict__ Bh, _Float16* __restrict__ Bl) {
  int idx = blockIdx.x * blockDim.x + threadIdx.x;
  if (idx >= NCOLS * KCAT) return;
  int kf = idx / KCAT, kk = idx - kf * KCAT;
  double v = 0.0;
  if (kf <= 400) {
    if (kk < KHALF) {
      int nt = kk;
      if (nt <= 400) {
        int ph = (kf * nt) % NFFT;
        v = ctab[ph];
      }
    } else {
      int nt = kk - KHALF;
      if (nt <= 400) {
        int ph = (kf * nt) % NFFT;
        v = -stab[ph];
      }
    }
  }
  float vf = (float)v;
  _Float16 h = (_Float16)vf;
  Bh[idx] = h;
  Bl[idx] = (_Float16)((vf - (float)h) * 2048.0f);
}

// ---------------- InverseMelScale: register-resident SGD, 1 wave per row --------
__global__ __launch_bounds__(64) void k_sgd(
    const float* __restrict__ spec0, const float* __restrict__ xmel,
    const float* __restrict__ fbT, const int* __restrict__ mlo,
    const int* __restrict__ mhi, const int* __restrict__ fm0,
    const float* __restrict__ fw0, const float* __restrict__ fw1,
    float* __restrict__ mag) {
  __shared__ float s_spec[NFREQ], s_diff[NMELS];
  const int row = blockIdx.x;
  const int b = row / TT, t = row - b * TT;
  const int tid = threadIdx.x;

  float spec[7], vel[7];
  int qm0[7], qm1[7];
  float qw0[7], qw1[7];
#pragma unroll
  for (int q = 0; q < 7; ++q) {
    int f = tid + 64 * q;
    bool v = f < NFREQ;
    float sv = v ? spec0[row * NFREQ + f] : 0.f;
    spec[q] = sv; vel[q] = 0.f;
    if (v) s_spec[f] = sv;
    int m0 = v ? fm0[f] : 0;
    int m1 = m0 + 1; if (m1 > NMELS - 1) m1 = NMELS - 1;
    qm0[q] = m0; qm1[q] = m1;
    qw0[q] = v ? fw0[f] : 0.f;
    qw1[q] = v ? fw1[f] : 0.f;
  }

  const int mA = tid;
  const int mB = tid + 64;
  const bool hasB = mB < NMELS;
  float melA = xmel[(b * NMELS + mA) * TT + t];
  float melB = hasB ? xmel[(b * NMELS + mB) * TT + t] : 0.f;
  int loA = mlo[mA];
  int hiA = mhi[mA];
  int loB = hasB ? mlo[mB] : 0;
  int hiB = hasB ? mhi[mB] : 0;
  float fbA[MAXSPAN], fbB[MAXSPAN];
#pragma unroll
  for (int i = 0; i < MAXSPAN; ++i) {
    fbA[i] = (loA + i < hiA) ? fbT[mA * NFREQ + loA + i] : 0.f;
    fbB[i] = (hasB && loB + i < hiB) ? fbT[mB * NFREQ + loB + i] : 0.f;
  }
  __syncthreads();

  for (int it = 0; it < SGDITERS; ++it) {
    float accA = 0.f, accB = 0.f;
#pragma unroll
    for (int i = 0; i < MAXSPAN; ++i) {
      int fA = loA + i; if (fA > 400) fA = 400;
      int fB = loB + i; if (fB > 400) fB = 400;
      accA = fmaf(fbA[i], s_spec[fA], accA);
      accB = fmaf(fbB[i], s_spec[fB], accB);
    }
    s_diff[mA] = melA - accA;
    if (hasB) s_diff[mB] = melB - accB;
    __syncthreads();
#pragma unroll
    for (int q = 0; q < 7; ++q) {
      int f = tid + 64 * q;
      if (f < NFREQ) {
        float d = s_diff[qm0[q]] * qw0[q] + s_diff[qm1[q]] * qw1[q];
        float g = -SGD_SCALE * d;
        float v = 0.9f * vel[q] + g;
        vel[q] = v;
        float sp = spec[q] - 0.1f * v;
        sp = sp > 0.f ? sp : 0.f;
        spec[q] = sp;
        s_spec[f] = sp;
      }
    }
    __syncthreads();
  }
#pragma unroll
  for (int q = 0; q < 7; ++q) {
    int f = tid + 64 * q;
    if (f < NFREQ) mag[row * NFREQ + f] = sqrtf(spec[q]);
  }
}

// ---------------- A1 prep (iteration 0; layout [Re@0|Im@416], pads zeroed) --------
__global__ void k_prep1(const float* __restrict__ mag, const float* __restrict__ ar,
                        const float* __restrict__ ai,
                        _Float16* __restrict__ Ah, _Float16* __restrict__ Al) {
  int kk = blockIdx.x * 256 + threadIdx.x;
  if (kk >= KCAT) return;
  int row = blockIdx.y;
  float v = 0.f;
  if (kk < KHALF) {
    int k = kk;
    if (k <= 400) { int gi = row * NFREQ + k; v = mag[gi] * ar[gi] * 256.0f; }
  } else {
    int k = kk - KHALF;
    if (k <= 400) { int gi = row * NFREQ + k; v = mag[gi] * ai[gi] * 256.0f; }
  }
  _Float16 h = (_Float16)v;
  size_t o = (size_t)row * KCAT + kk;
  Ah[o] = h;
  Al[o] = (_Float16)((v - (float)h) * 2048.0f);
}

// ---------------- shared GEMM macros (double-buffered, 1 barrier/chunk) ----------
#define GEMM_STAGE(BUF)                                                         \
    *(uint4*)&As_h[BUF][sr * 40 + sk] = pa_h;                                   \
    *(uint4*)&As_l[BUF][sr * 40 + sk] = pa_l;                                   \
    *(uint4*)&Bs_h[BUF][sr * 40 + sk] = pb_h;                                   \
    *(uint4*)&Bs_l[BUF][sr * 40 + sk] = pb_l;

#define GEMM_COMPUTE(BUF, A0, A1v)                                              \
  {                                                                             \
    half8 a_h[2], a_l[2];                                                       \
    _Pragma("unroll")                                                           \
    for (int i = 0; i < 2; ++i) {                                               \
      int m = wm * 32 + i * 16 + lm;                                            \
      a_h[i] = *(const half8*)&As_h[BUF][m * 40 + qd * 8];                      \
      a_l[i] = *(const half8*)&As_l[BUF][m * 40 + qd * 8];                      \
    }                                                                           \
    _Pragma("unroll")                                                           \
    for (int j = 0; j < 2; ++j) {                                               \
      int n = wn * 32 + j * 16 + lm;                                            \
      half8 b_h = *(const half8*)&Bs_h[BUF][n * 40 + qd * 8];                   \
      half8 b_l = *(const half8*)&Bs_l[BUF][n * 40 + qd * 8];                   \
      _Pragma("unroll")                                                         \
      for (int i = 0; i < 2; ++i) {                                             \
        A0[i][j]  = __builtin_amdgcn_mfma_f32_16x16x32_f16(a_h[i], b_h, A0[i][j], 0, 0, 0);  \
        A1v[i][j] = __builtin_amdgcn_mfma_f32_16x16x32_f16(a_h[i], b_l, A1v[i][j], 0, 0, 0); \
        A1v[i][j] = __builtin_amdgcn_mfma_f32_16x16x32_f16(a_l[i], b_h, A1v[i][j], 0, 0, 0); \
      }                                                                         \
    }                                                                           \
  }

// K=832, 26 chunks of 32; chunks 0..12 -> (ac0,ac1), 13..25 -> (as0,as1).
#define GEMM_LOOP                                                               \
  uint4 pa_h = *(const uint4*)&Ah[abase];                                       \
  uint4 pa_l = *(const uint4*)&Al[abase];                                       \
  uint4 pb_h = *(const uint4*)&Bh[bbase];                                       \
  uint4 pb_l = *(const uint4*)&Bl[bbase];                                       \
  GEMM_STAGE(0)                                                                 \
  _Pragma("unroll 2")                                                           \
  for (int c = 0; c < 26; ++c) {                                                \
    __syncthreads();                                                            \
    if (c < 25) {                                                               \
      int off = (c + 1) * 32;                                                   \
      pa_h = *(const uint4*)&Ah[abase + off];                                   \
      pa_l = *(const uint4*)&Al[abase + off];                                   \
      pb_h = *(const uint4*)&Bh[bbase + off];                                   \
      pb_l = *(const uint4*)&Bl[bbase + off];                                   \
    }                                                                           \
    const int bf = c & 1;                                                       \
    if (c < 13) { GEMM_COMPUTE(bf, ac0, ac1) } else { GEMM_COMPUTE(bf, as0, as1) } \
    if (c < 25) { GEMM_STAGE(bf ^ 1) }                                          \
  }

// ---------------- mm1: frames via C/S symmetric irfft ----------------
// 64x64 tile, 4 waves 2x2 of 32x32; grid (7,64)
__global__ __launch_bounds__(256, 2) void k_mm1(
    const _Float16* __restrict__ Ah, const _Float16* __restrict__ Al,
    const _Float16* __restrict__ Bh, const _Float16* __restrict__ Bl,
    const float* __restrict__ win, float* __restrict__ frames) {
  __shared__ __align__(16) _Float16 As_h[2][64 * 40], As_l[2][64 * 40];
  __shared__ __align__(16) _Float16 Bs_h[2][64 * 40], Bs_l[2][64 * 40];
  const int t = threadIdx.x;
  const int row0 = blockIdx.y * 64;
  const int col0 = blockIdx.x * 64;
  const int sr = t >> 2, sk = (t & 3) * 8;
  const int lane = t & 63, wv = t >> 6;
  const int wm = wv & 1, wn = wv >> 1;
  const int lm = lane & 15, qd = lane >> 4;
  f32x4 ac0[2][2] = {}, ac1[2][2] = {}, as0[2][2] = {}, as1[2][2] = {};
  const size_t abase = (size_t)(row0 + sr) * KCAT + sk;
  const size_t bbase = (size_t)(col0 + sr) * KCAT + sk;
  GEMM_LOOP
#pragma unroll
  for (int j = 0; j < 2; ++j) {
    int col = col0 + wn * 32 + j * 16 + lm;
    if (col <= 400) {
      float wA = win[col];
      bool mir = (col >= 1 && col <= 399);
      float wB = mir ? win[800 - col] : 0.f;
#pragma unroll
      for (int i = 0; i < 2; ++i)
#pragma unroll
        for (int r = 0; r < 4; ++r) {
          int row = row0 + wm * 32 + i * 16 + qd * 4 + r;
          float Cv = ac0[i][j][r] + ac1[i][j][r] * LO_INV;
          float Sv = as0[i][j][r] + as1[i][j][r] * LO_INV;
          frames[(size_t)row * NFFT + col] = (Cv + Sv) * wA;
          if (mir) frames[(size_t)row * NFFT + (800 - col)] = (Cv - Sv) * wB;
        }
    }
  }
}

// ---------------- fused OLA + window + E/O split prep ----------------
__device__ inline float sample_y(const float* __restrict__ fb_,
                                 const float* __restrict__ wsinv, int j) {
  int jm = (j < PADW) ? (NFFT - j) : ((j < PADW + LOUTW) ? j : (205198 - j));
  int t1 = jm / HOPSZ; if (t1 > TT - 1) t1 = TT - 1;
  int t0 = (jm - (NFFT - HOPSZ)) / HOPSZ; if (t0 < 0) t0 = 0;
  float s = 0.f;
  for (int t = t0; t <= t1; ++t) s += fb_[t * NFFT + (jm - t * HOPSZ)];
  return s * wsinv[jm];
}

__global__ void k_olaprep(const float* __restrict__ frames, const float* __restrict__ wsinv,
                          const float* __restrict__ win,
                          _Float16* __restrict__ A2h, _Float16* __restrict__ A2l) {
  int idx = blockIdx.x * 256 + threadIdx.x;      // row*416 + n
  if (idx >= NROWS * KHALF) return;
  int row = idx / KHALF, n = idx - row * KHALF;
  size_t ab = (size_t)row * KCAT;
  if (n > 400) {                                  // K pads
    A2h[ab + n] = (_Float16)0.f; A2l[ab + n] = (_Float16)0.f;
    A2h[ab + KHALF + n] = (_Float16)0.f; A2l[ab + KHALF + n] = (_Float16)0.f;
    return;
  }
  int b = row >> 9, tt = row & 511;
  const float* fb_ = frames + (size_t)b * TT * NFFT;
  int start = tt * HOPSZ;
  float x1 = sample_y(fb_, wsinv, start + n) * win[n] * 256.0f;
  float x2 = 0.f;
  // mirror only n in [1,399]: n==400 self-maps; n==0 mirror OOB
  if (n >= 1 && n <= 399)
    x2 = sample_y(fb_, wsinv, start + 800 - n) * win[800 - n] * 256.0f;
  float E = x1 + x2, O = x1 - x2;
  _Float16 Eh = (_Float16)E;
  A2h[ab + n] = Eh;
  A2l[ab + n] = (_Float16)((E - (float)Eh) * 2048.0f);
  _Float16 Oh = (_Float16)O;
  A2h[ab + KHALF + n] = Oh;
  A2l[ab + KHALF + n] = (_Float16)((O - (float)Oh) * 2048.0f);
}

// ---------------- mm2: rfft (Re/Im symmetric) + momentum + normalize + A1' -------
__global__ __launch_bounds__(256, 2) void k_mm2(
    const _Float16* __restrict__ Ah, const _Float16* __restrict__ Al,
    const _Float16* __restrict__ Bh, const _Float16* __restrict__ Bl,
    const float* __restrict__ mag,
    float* __restrict__ tppr, float* __restrict__ tppi,
    _Float16* __restrict__ A1h, _Float16* __restrict__ A1l, float beta) {
  __shared__ __align__(16) _Float16 As_h[2][64 * 40], As_l[2][64 * 40];
  __shared__ __align__(16) _Float16 Bs_h[2][64 * 40], Bs_l[2][64 * 40];
  const int t = threadIdx.x;
  const int row0 = blockIdx.y * 64;
  const int col0 = blockIdx.x * 64;
  const int sr = t >> 2, sk = (t & 3) * 8;
  const int lane = t & 63, wv = t >> 6;
  const int wm = wv & 1, wn = wv >> 1;
  const int lm = lane & 15, qd = lane >> 4;
  f32x4 ac0[2][2] = {}, ac1[2][2] = {}, as0[2][2] = {}, as1[2][2] = {};
  const size_t abase = (size_t)(row0 + sr) * KCAT + sk;
  const size_t bbase = (size_t)(col0 + sr) * KCAT + sk;
  GEMM_LOOP
#pragma unroll
  for (int j = 0; j < 2; ++j) {
    int col = col0 + wn * 32 + j * 16 + lm;
    if (col <= 400) {
#pragma unroll
      for (int i = 0; i < 2; ++i)
#pragma unroll
        for (int r = 0; r < 4; ++r) {
          int row = row0 + wm * 32 + i * 16 + qd * 4 + r;
          int idx = row * NFREQ + col;
          float rr = ac0[i][j][r] + ac1[i][j][r] * LO_INV;   // Re (x256 scale)
          float ri = as0[i][j][r] + as1[i][j][r] * LO_INV;   // Im
          float nr = rr - beta * tppr[idx];
          float ni = ri - beta * tppi[idx];
          tppr[idx] = rr; tppi[idx] = ri;
          float den = sqrtf(nr * nr + ni * ni) + 1e-16f;
          float arv = nr / den, aiv = ni / den;
          float mg = mag[idx] * 256.0f;
          size_t ab = (size_t)row * KCAT;
          float v1 = mg * arv;
          _Float16 h1 = (_Float16)v1;
          A1h[ab + col] = h1;
          A1l[ab + col] = (_Float16)((v1 - (float)h1) * 2048.0f);
          float v2 = mg * aiv;
          _Float16 h2 = (_Float16)v2;
          A1h[ab + KHALF + col] = h2;
          A1l[ab + KHALF + col] = (_Float16)((v2 - (float)h2) * 2048.0f);
        }
    }
  }
}

// ---------------- final overlap-add (full y, once; exact divide) ----------------
__global__ void k_ola(const float* __restrict__ frames, const float* __restrict__ wsqs,
                      float* __restrict__ y) {
  int idx = blockIdx.x * blockDim.x + threadIdx.x;
  if (idx >= NB * LY) return;
  int b = idx / LY, j = idx - b * LY;
  int t1 = j / HOPSZ; if (t1 > TT - 1) t1 = TT - 1;
  int t0 = (j - (NFFT - HOPSZ)) / HOPSZ; if (t0 < 0) t0 = 0;
  const float* fb_ = frames + (size_t)b * TT * NFFT;
  float s = 0.f;
  for (int t = t0; t <= t1; ++t) s += fb_[t * NFFT + (j - t * HOPSZ)];
  y[idx] = s / wsqs[j];
}

// ---------------- epilogue: peak-normalize ----------------
__global__ void k_absmax(const float* __restrict__ y, float* __restrict__ peak) {
  __shared__ float red[256];
  int b = blockIdx.x;
  const float* yb = y + (size_t)b * LY + PADW;
  float mx = 0.f;
  for (int j = threadIdx.x; j < LOUTW; j += 256) mx = fmaxf(mx, fabsf(yb[j]));
  red[threadIdx.x] = mx;
  __syncthreads();
  for (int s2 = 128; s2 > 0; s2 >>= 1) {
    if (threadIdx.x < s2) red[threadIdx.x] = fmaxf(red[threadIdx.x], red[threadIdx.x + s2]);
    __syncthreads();
  }
  if (threadIdx.x == 0) peak[b] = red[0];
}

__global__ void k_scale(const float* __restrict__ y, const float* __restrict__ peak,
                        float* __restrict__ out, float target) {
  int idx = blockIdx.x * blockDim.x + threadIdx.x;
  if (idx >= NB * LOUTW) return;
  int b = idx / LOUTW, j = idx - b * LOUTW;
  out[idx] = y[(size_t)b * LY + PADW + j] * (target / peak[b]);
}

__global__ void k_zero2(float* __restrict__ a, float* __restrict__ b, int n) {
  int i = blockIdx.x * blockDim.x + threadIdx.x;
  if (i < n) { a[i] = 0.f; b[i] = 0.f; }
}

// ---------------- host ----------------
extern "C" void kernel_launch(void* const* d_in, const int* in_sizes, int n_in,
                              void* d_out, int out_size, void* d_ws, size_t ws_size,
                              hipStream_t stream) {
  const float* xmel = (const float*)d_in[0];   // (8, 80, 512) f32
  float* out = (float*)d_out;                  // (8, 1, 102200) f32

  char* p = (char*)d_ws;
  auto alloc = [&](size_t nbytes) -> void* {
    void* r = (void*)p;
    p += (nbytes + 255) & ~(size_t)255;
    return r;
  };
  float* mag  = (float*)alloc((size_t)NSPEC * 4);
  float* ar   = (float*)alloc((size_t)NSPEC * 4);
  float* ai   = (float*)alloc((size_t)NSPEC * 4);
  float* tpr  = (float*)alloc((size_t)NSPEC * 4);
  float* tpi  = (float*)alloc((size_t)NSPEC * 4);
  float* y    = (float*)alloc((size_t)NB * LY * 4);
  float* win  = (float*)alloc(NFFT * 4);
  float* wsqs = (float*)alloc((size_t)LY * 4);
  float* wsinv= (float*)alloc((size_t)LY * 4);
  double* ctab= (double*)alloc(NFFT * 8);
  double* stab= (double*)alloc(NFFT * 8);
  float* fbT  = (float*)alloc((size_t)NMELS * NFREQ * 4);
  float* fw0  = (float*)alloc(NFREQ * 4);
  float* fw1  = (float*)alloc(NFREQ * 4);
  float* peak = (float*)alloc(NB * 4);
  int* fm0    = (int*)alloc(NFREQ * 4);
  int* mlo    = (int*)alloc(NMELS * 4);
  int* mhi    = (int*)alloc(NMELS * 4);
  float* frames = (float*)alloc((size_t)NROWS * NFFT * 4);
  float* spec0 = frames;  // alias: consumed by k_sgd before frames written
  _Float16* A1h = (_Float16*)alloc((size_t)NROWS * KCAT * 2);
  _Float16* A1l = (_Float16*)alloc((size_t)NROWS * KCAT * 2);
  _Float16* A2h = (_Float16*)alloc((size_t)NROWS * KCAT * 2);
  _Float16* A2l = (_Float16*)alloc((size_t)NROWS * KCAT * 2);
  _Float16* B1h = (_Float16*)alloc((size_t)NCOLS * KCAT * 2);
  _Float16* B1l = (_Float16*)alloc((size_t)NCOLS * KCAT * 2);
  _Float16* B2h = (_Float16*)alloc((size_t)NCOLS * KCAT * 2);
  _Float16* B2l = (_Float16*)alloc((size_t)NCOLS * KCAT * 2);

  if ((size_t)(p - (char*)d_ws) > ws_size) return;  // insufficient scratch

  // derived threefry keys (jax partitionable split)
  unsigned k1a, k1b, k2a, k2b, kra, krb, kia, kib;
  {
    unsigned o0, o1;
    tf2x32(0u, 1u, 0u, 0u, o0, o1); k1a = o0; k1b = o1;
    tf2x32(0u, 1u, 0u, 1u, o0, o1); k2a = o0; k2b = o1;
    tf2x32(k2a, k2b, 0u, 0u, o0, o1); kra = o0; krb = o1;
    tf2x32(k2a, k2b, 0u, 1u, o0, o1); kia = o0; kib = o1;
  }

  // init (trig table first; all consumers read it)
  k_trig<<<(NFFT + 255) / 256, 256, 0, stream>>>(ctab, stab);
  k_fb<<<2, 256, 0, stream>>>(fbT, fm0, fw0, fw1);
  k_ranges<<<1, 128, 0, stream>>>(fbT, mlo, mhi);
  k_wsq<<<(LY + 255) / 256, 256, 0, stream>>>(ctab, wsqs, wsinv, win);
  k_tabs1<<<(NCOLS * KCAT + 255) / 256, 256, 0, stream>>>(ctab, stab, B1h, B1l);
  k_tabs2<<<(NCOLS * KCAT + 255) / 256, 256, 0, stream>>>(ctab, stab, B2h, B2l);
  k_zero2<<<(NSPEC + 255) / 256, 256, 0, stream>>>(tpr, tpi, NSPEC);
  k_rand_spec<<<(NSPEC + 255) / 256, 256, 0, stream>>>(k1a, k1b, spec0);
  k_rand_ang<<<(NSPEC + 255) / 256, 256, 0, stream>>>(kra, krb, kia, kib, ar, ai);

  // InverseMelScale (1 wave per (b,t) row, register-resident)
  k_sgd<<<NROWS, 64, 0, stream>>>(spec0, xmel, fbT, mlo, mhi, fm0, fw0, fw1, mag);

  // iteration-0 A1 (layout [Re@0|Im@416], pads zeroed once)
  k_prep1<<<dim3(4, NROWS), 256, 0, stream>>>(mag, ar, ai, A1h, A1l);

  // Griffin-Lim: 3 dispatches per iteration
  const float beta = (float)(0.99 / 1.99);
  for (int it = 0; it < GLITERS; ++it) {
    k_mm1<<<dim3(7, 64), 256, 0, stream>>>(A1h, A1l, B1h, B1l, win, frames);
    k_olaprep<<<(NROWS * KHALF + 255) / 256, 256, 0, stream>>>(frames, wsinv, win, A2h, A2l);
    k_mm2<<<dim3(7, 64), 256, 0, stream>>>(A2h, A2l, B2h, B2l,
                                           mag, tpr, tpi, A1h, A1l, beta);
  }
  // final istft with final angles (A1 written by last k_mm2)
  k_mm1<<<dim3(7, 64), 256, 0, stream>>>(A1h, A1l, B1h, B1l, win, frames);
  k_ola<<<(NB * LY + 255) / 256, 256, 0, stream>>>(frames, wsqs, y);

  // normalize
  k_absmax<<<NB, 256, 0, stream>>>(y, peak);
  const float target = (float)pow(10.0, -0.1 / 20.0);
  k_scale<<<(NB * LOUTW + 255) / 256, 256, 0, stream>>>(y, peak, out, target);
}

// Round 14
// 2499.882 us; speedup vs baseline: 4.8401x; 1.0039x over previous
//
#include <hip/hip_runtime.h>
#include <math.h>

// ---------------- problem constants ----------------
#define NB 8
#define NMELS 80
#define TT 512
#define NFREQ 401
#define NFFT 800
#define HOPSZ 200
#define NROWS (NB*TT)          // 4096 frames
#define LY 103000              // untrimmed istft length
#define LOUTW 102200
#define PADW 400
#define NSPEC (NROWS*NFREQ)    // 1640448
#define GLITERS 30
#define SGDITERS 50
#define SGD_SCALE 0.003125f    // 2/(B*n_mels)
#define KCAT 832               // concatenated K: [part0 416 | part1 416]
#define KHALF 416
#define NCOLS 448              // padded output cols (7*64), valid [0,400]
#define MAXSPAN 24             // max mel-band width in bins (measured 21)
#define TABN (NCOLS*KCAT)      // 372736
// scales: A x256, B1 x16 (/800 dropped), lo parts x2048
#define WSQ_SCALE 3276800.0f   // 800*16*256
#define LO_INV 4.8828125e-4f   // 2^-11

#define TWO_PI_D 6.283185307179586476925286766559

typedef _Float16 half8 __attribute__((ext_vector_type(8)));
typedef float f32x4 __attribute__((ext_vector_type(4)));

// ---------------- threefry2x32 (20 rounds) ----------------
__host__ __device__ inline void tf2x32(unsigned k0, unsigned k1,
                                       unsigned x0, unsigned x1,
                                       unsigned& o0, unsigned& o1) {
  unsigned ks0 = k0, ks1 = k1, ks2 = k0 ^ k1 ^ 0x1BD11BDAu;
  x0 += ks0; x1 += ks1;
#define TF_R(r) { x0 += x1; x1 = (x1 << (r)) | (x1 >> (32 - (r))); x1 ^= x0; }
  TF_R(13) TF_R(15) TF_R(26) TF_R(6)
  x0 += ks1; x1 += ks2 + 1u;
  TF_R(17) TF_R(29) TF_R(16) TF_R(24)
  x0 += ks2; x1 += ks0 + 2u;
  TF_R(13) TF_R(15) TF_R(26) TF_R(6)
  x0 += ks0; x1 += ks1 + 3u;
  TF_R(17) TF_R(29) TF_R(16) TF_R(24)
  x0 += ks1; x1 += ks2 + 4u;
  TF_R(13) TF_R(15) TF_R(26) TF_R(6)
  x0 += ks2; x1 += ks0 + 5u;
#undef TF_R
  o0 = x0; o1 = x1;
}

__device__ inline float u01(unsigned bits) {
  unsigned u = (bits >> 9) | 0x3f800000u;
  return __uint_as_float(u) - 1.0f;
}

__device__ inline int ang_map(int g) {
  int b = g / (NFREQ * TT);
  int r = g - b * (NFREQ * TT);
  int f = r / TT;
  int t = r - f * TT;
  return (b * TT + t) * NFREQ + f;
}

// ---------------- mel helpers ----------------
__device__ inline double mel2hz_d(double mel) {
  return 700.0 * (pow(10.0, mel / 2595.0) - 1.0);
}

// ---------------- init A: trig tables + mel filterbank ----------------
__global__ void k_initA(double* __restrict__ ctab, double* __restrict__ stab,
                        float* __restrict__ fbT, int* __restrict__ fm0,
                        float* __restrict__ fw0, float* __restrict__ fw1) {
  int i = blockIdx.x * 256 + threadIdx.x;
  if (i < NFFT) {
    double ang = (double)i * (TWO_PI_D / 800.0);
    ctab[i] = cos(ang);
    stab[i] = sin(ang);
  }
  if (i < NFREQ) {
    const int f = i;
    const double freq = 10.0 * (double)f;
    const double melmax = 2595.0 * log10(1.0 + 4000.0 / 700.0);
    const double step = melmax / 81.0;
    int first = -1; float w0v = 0.f, w1v = 0.f;
    double p0 = 0.0;
    double p1 = mel2hz_d(step);
    for (int m = 0; m < NMELS; ++m) {
      double m2 = (m + 2 == 81) ? melmax : (double)(m + 2) * step;
      double p2 = mel2hz_d(m2);
      double down = (freq - p0) / (p1 - p0);
      double up   = (p2 - freq) / (p2 - p1);
      double v = down < up ? down : up;
      if (v < 0.0) v = 0.0;
      float vf = (float)v;
      fbT[m * NFREQ + f] = vf;
      if (vf > 0.f) {
        if (first < 0) { first = m; w0v = vf; }
        else if (m == first + 1) { w1v = vf; }
      }
      p0 = p1; p1 = p2;
    }
    fm0[f] = first < 0 ? 0 : first;
    fw0[f] = first < 0 ? 0.f : w0v;
    fw1[f] = w1v;
  }
}

__global__ void k_ranges(const float* __restrict__ fbT, int* __restrict__ mlo,
                         int* __restrict__ mhi) {
  int m = threadIdx.x;
  if (m >= NMELS) return;
  int lo = NFREQ, hi = 0;
  for (int f = 0; f < NFREQ; ++f)
    if (fbT[m * NFREQ + f] > 0.f) { if (lo == NFREQ) lo = f; hi = f + 1; }
  mlo[m] = lo; mhi[m] = hi < lo ? lo : hi;
}

// ---------------- init B: wsq/win + both f16-split DFT tables ----------------
// index range: [0,LY) -> wsq; [LY, LY+TABN) -> tabs1; [LY+TABN, LY+2*TABN) -> tabs2
__global__ void k_initB(const double* __restrict__ ctab, const double* __restrict__ stab,
                        float* __restrict__ wsqs, float* __restrict__ wsinv,
                        float* __restrict__ win,
                        _Float16* __restrict__ B1h, _Float16* __restrict__ B1l,
                        _Float16* __restrict__ B2h, _Float16* __restrict__ B2l) {
  int g = blockIdx.x * 256 + threadIdx.x;
  if (g < LY) {
    int j = g;
    if (j < NFFT) win[j] = (float)(0.5 - 0.5 * ctab[j]);
    int t1 = j / HOPSZ; if (t1 > TT - 1) t1 = TT - 1;
    int t0 = (j - (NFFT - HOPSZ)) / HOPSZ; if (t0 < 0) t0 = 0;
    float s = 0.f;
    for (int t = t0; t <= t1; ++t) {
      float w = (float)(0.5 - 0.5 * ctab[j - t * HOPSZ]);
      s += w * w;
    }
    s = fmaxf(s, 1e-11f);
    wsqs[j] = WSQ_SCALE * s;
    wsinv[j] = (float)(1.0 / ((double)WSQ_SCALE * (double)s));  // single rounding
    return;
  }
  int g1 = g - LY;
  if (g1 < TABN) {
    int n = g1 / KCAT, kk = g1 - n * KCAT;
    double v = 0.0;
    if (n <= 400) {
      if (kk < KHALF) {
        int k = kk;
        if (k <= 400) {
          double ak = (k == 0 || k == 400) ? 1.0 : 2.0;
          int ph = (k * n) % NFFT;
          v = 16.0 * ak * ctab[ph];
        }
      } else {
        int k = kk - KHALF;
        if (k <= 400) {
          int ph = (k * n) % NFFT;
          v = -32.0 * stab[ph];
        }
      }
    }
    float vf = (float)v;
    _Float16 h = (_Float16)vf;
    B1h[g1] = h;
    B1l[g1] = (_Float16)((vf - (float)h) * 2048.0f);
    return;
  }
  int g2 = g1 - TABN;
  if (g2 < TABN) {
    int kf = g2 / KCAT, kk = g2 - kf * KCAT;
    double v = 0.0;
    if (kf <= 400) {
      if (kk < KHALF) {
        int nt = kk;
        if (nt <= 400) {
          int ph = (kf * nt) % NFFT;
          v = ctab[ph];
        }
      } else {
        int nt = kk - KHALF;
        if (nt <= 400) {
          int ph = (kf * nt) % NFFT;
          v = -stab[ph];
        }
      }
    }
    float vf = (float)v;
    _Float16 h = (_Float16)vf;
    B2h[g2] = h;
    B2l[g2] = (_Float16)((vf - (float)h) * 2048.0f);
  }
}

// ---------------- init C: zero momentum + all RNG draws (one pass) ----------------
__global__ void k_initC(unsigned k1a, unsigned k1b, unsigned kra, unsigned krb,
                        unsigned kia, unsigned kib,
                        float* __restrict__ spec, float* __restrict__ ar,
                        float* __restrict__ ai, float* __restrict__ tpr,
                        float* __restrict__ tpi) {
  int i = blockIdx.x * 256 + threadIdx.x;
  if (i >= NSPEC) return;
  tpr[i] = 0.f; tpi[i] = 0.f;
  unsigned o0, o1;
  tf2x32(k1a, k1b, 0u, (unsigned)i, o0, o1);
  spec[i] = u01(o0 ^ o1);                       // partitionable 32-bit fold
  int d = ang_map(i);
  tf2x32(kra, krb, 0u, (unsigned)i, o0, o1); ar[d] = u01(o0 ^ o1);
  tf2x32(kia, kib, 0u, (unsigned)i, o0, o1); ai[d] = u01(o0 ^ o1);
}

// ---------------- InverseMelScale: 2 rows per 128-thread block -----------------
// Each wave handles one row with private LDS slices; per-row math bit-identical
// to the 64-thread version (uniform loop counts -> barriers are safe).
__global__ __launch_bounds__(128) void k_sgd(
    const float* __restrict__ spec0, const float* __restrict__ xmel,
    const float* __restrict__ fbT, const int* __restrict__ mlo,
    const int* __restrict__ mhi, const int* __restrict__ fm0,
    const float* __restrict__ fw0, const float* __restrict__ fw1,
    float* __restrict__ mag) {
  __shared__ float s_spec[2][NFREQ], s_diff[2][NMELS];
  const int w = threadIdx.x >> 6;        // wave id 0/1
  const int tid = threadIdx.x & 63;
  const int row = blockIdx.x * 2 + w;
  const int b = row / TT, t = row - b * TT;

  float spec[7], vel[7];
  int qm0[7], qm1[7];
  float qw0[7], qw1[7];
#pragma unroll
  for (int q = 0; q < 7; ++q) {
    int f = tid + 64 * q;
    bool v = f < NFREQ;
    float sv = v ? spec0[row * NFREQ + f] : 0.f;
    spec[q] = sv; vel[q] = 0.f;
    if (v) s_spec[w][f] = sv;
    int m0 = v ? fm0[f] : 0;
    int m1 = m0 + 1; if (m1 > NMELS - 1) m1 = NMELS - 1;
    qm0[q] = m0; qm1[q] = m1;
    qw0[q] = v ? fw0[f] : 0.f;
    qw1[q] = v ? fw1[f] : 0.f;
  }

  const int mA = tid;
  const int mB = tid + 64;
  const bool hasB = mB < NMELS;
  float melA = xmel[(b * NMELS + mA) * TT + t];
  float melB = hasB ? xmel[(b * NMELS + mB) * TT + t] : 0.f;
  int loA = mlo[mA];
  int hiA = mhi[mA];
  int loB = hasB ? mlo[mB] : 0;
  int hiB = hasB ? mhi[mB] : 0;
  float fbA[MAXSPAN], fbB[MAXSPAN];
#pragma unroll
  for (int i = 0; i < MAXSPAN; ++i) {
    fbA[i] = (loA + i < hiA) ? fbT[mA * NFREQ + loA + i] : 0.f;
    fbB[i] = (hasB && loB + i < hiB) ? fbT[mB * NFREQ + loB + i] : 0.f;
  }
  __syncthreads();

  for (int it = 0; it < SGDITERS; ++it) {
    float accA = 0.f, accB = 0.f;
#pragma unroll
    for (int i = 0; i < MAXSPAN; ++i) {
      int fA = loA + i; if (fA > 400) fA = 400;
      int fB = loB + i; if (fB > 400) fB = 400;
      accA = fmaf(fbA[i], s_spec[w][fA], accA);
      accB = fmaf(fbB[i], s_spec[w][fB], accB);
    }
    s_diff[w][mA] = melA - accA;
    if (hasB) s_diff[w][mB] = melB - accB;
    __syncthreads();
#pragma unroll
    for (int q = 0; q < 7; ++q) {
      int f = tid + 64 * q;
      if (f < NFREQ) {
        float d = s_diff[w][qm0[q]] * qw0[q] + s_diff[w][qm1[q]] * qw1[q];
        float g = -SGD_SCALE * d;
        float v = 0.9f * vel[q] + g;
        vel[q] = v;
        float sp = spec[q] - 0.1f * v;
        sp = sp > 0.f ? sp : 0.f;
        spec[q] = sp;
        s_spec[w][f] = sp;
      }
    }
    __syncthreads();
  }
#pragma unroll
  for (int q = 0; q < 7; ++q) {
    int f = tid + 64 * q;
    if (f < NFREQ) mag[row * NFREQ + f] = sqrtf(spec[q]);
  }
}

// ---------------- A1 prep (iteration 0; layout [Re@0|Im@416], pads zeroed) --------
__global__ void k_prep1(const float* __restrict__ mag, const float* __restrict__ ar,
                        const float* __restrict__ ai,
                        _Float16* __restrict__ Ah, _Float16* __restrict__ Al) {
  int kk = blockIdx.x * 256 + threadIdx.x;
  if (kk >= KCAT) return;
  int row = blockIdx.y;
  float v = 0.f;
  if (kk < KHALF) {
    int k = kk;
    if (k <= 400) { int gi = row * NFREQ + k; v = mag[gi] * ar[gi] * 256.0f; }
  } else {
    int k = kk - KHALF;
    if (k <= 400) { int gi = row * NFREQ + k; v = mag[gi] * ai[gi] * 256.0f; }
  }
  _Float16 h = (_Float16)v;
  size_t o = (size_t)row * KCAT + kk;
  Ah[o] = h;
  Al[o] = (_Float16)((v - (float)h) * 2048.0f);
}

// ---------------- shared GEMM macros (double-buffered, 1 barrier/chunk) ----------
#define GEMM_STAGE(BUF)                                                         \
    *(uint4*)&As_h[BUF][sr * 40 + sk] = pa_h;                                   \
    *(uint4*)&As_l[BUF][sr * 40 + sk] = pa_l;                                   \
    *(uint4*)&Bs_h[BUF][sr * 40 + sk] = pb_h;                                   \
    *(uint4*)&Bs_l[BUF][sr * 40 + sk] = pb_l;

#define GEMM_COMPUTE(BUF, A0, A1v)                                              \
  {                                                                             \
    half8 a_h[2], a_l[2];                                                       \
    _Pragma("unroll")                                                           \
    for (int i = 0; i < 2; ++i) {                                               \
      int m = wm * 32 + i * 16 + lm;                                            \
      a_h[i] = *(const half8*)&As_h[BUF][m * 40 + qd * 8];                      \
      a_l[i] = *(const half8*)&As_l[BUF][m * 40 + qd * 8];                      \
    }                                                                           \
    _Pragma("unroll")                                                           \
    for (int j = 0; j < 2; ++j) {                                               \
      int n = wn * 32 + j * 16 + lm;                                            \
      half8 b_h = *(const half8*)&Bs_h[BUF][n * 40 + qd * 8];                   \
      half8 b_l = *(const half8*)&Bs_l[BUF][n * 40 + qd * 8];                   \
      _Pragma("unroll")                                                         \
      for (int i = 0; i < 2; ++i) {                                             \
        A0[i][j]  = __builtin_amdgcn_mfma_f32_16x16x32_f16(a_h[i], b_h, A0[i][j], 0, 0, 0);  \
        A1v[i][j] = __builtin_amdgcn_mfma_f32_16x16x32_f16(a_h[i], b_l, A1v[i][j], 0, 0, 0); \
        A1v[i][j] = __builtin_amdgcn_mfma_f32_16x16x32_f16(a_l[i], b_h, A1v[i][j], 0, 0, 0); \
      }                                                                         \
    }                                                                           \
  }

// K=832, 26 chunks of 32; chunks 0..12 -> (ac0,ac1), 13..25 -> (as0,as1).
#define GEMM_LOOP                                                               \
  uint4 pa_h = *(const uint4*)&Ah[abase];                                       \
  uint4 pa_l = *(const uint4*)&Al[abase];                                       \
  uint4 pb_h = *(const uint4*)&Bh[bbase];                                       \
  uint4 pb_l = *(const uint4*)&Bl[bbase];                                       \
  GEMM_STAGE(0)                                                                 \
  _Pragma("unroll 2")                                                           \
  for (int c = 0; c < 26; ++c) {                                                \
    __syncthreads();                                                            \
    if (c < 25) {                                                               \
      int off = (c + 1) * 32;                                                   \
      pa_h = *(const uint4*)&Ah[abase + off];                                   \
      pa_l = *(const uint4*)&Al[abase + off];                                   \
      pb_h = *(const uint4*)&Bh[bbase + off];                                   \
      pb_l = *(const uint4*)&Bl[bbase + off];                                   \
    }                                                                           \
    const int bf = c & 1;                                                       \
    if (c < 13) { GEMM_COMPUTE(bf, ac0, ac1) } else { GEMM_COMPUTE(bf, as0, as1) } \
    if (c < 25) { GEMM_STAGE(bf ^ 1) }                                          \
  }

// ---------------- mm1: frames via C/S symmetric irfft ----------------
// 64x64 tile, 4 waves 2x2 of 32x32; grid (7,64)
__global__ __launch_bounds__(256, 2) void k_mm1(
    const _Float16* __restrict__ Ah, const _Float16* __restrict__ Al,
    const _Float16* __restrict__ Bh, const _Float16* __restrict__ Bl,
    const float* __restrict__ win, float* __restrict__ frames) {
  __shared__ __align__(16) _Float16 As_h[2][64 * 40], As_l[2][64 * 40];
  __shared__ __align__(16) _Float16 Bs_h[2][64 * 40], Bs_l[2][64 * 40];
  const int t = threadIdx.x;
  const int row0 = blockIdx.y * 64;
  const int col0 = blockIdx.x * 64;
  const int sr = t >> 2, sk = (t & 3) * 8;
  const int lane = t & 63, wv = t >> 6;
  const int wm = wv & 1, wn = wv >> 1;
  const int lm = lane & 15, qd = lane >> 4;
  f32x4 ac0[2][2] = {}, ac1[2][2] = {}, as0[2][2] = {}, as1[2][2] = {};
  const size_t abase = (size_t)(row0 + sr) * KCAT + sk;
  const size_t bbase = (size_t)(col0 + sr) * KCAT + sk;
  GEMM_LOOP
#pragma unroll
  for (int j = 0; j < 2; ++j) {
    int col = col0 + wn * 32 + j * 16 + lm;
    if (col <= 400) {
      float wA = win[col];
      bool mir = (col >= 1 && col <= 399);
      float wB = mir ? win[800 - col] : 0.f;
#pragma unroll
      for (int i = 0; i < 2; ++i)
#pragma unroll
        for (int r = 0; r < 4; ++r) {
          int row = row0 + wm * 32 + i * 16 + qd * 4 + r;
          float Cv = ac0[i][j][r] + ac1[i][j][r] * LO_INV;
          float Sv = as0[i][j][r] + as1[i][j][r] * LO_INV;
          frames[(size_t)row * NFFT + col] = (Cv + Sv) * wA;
          if (mir) frames[(size_t)row * NFFT + (800 - col)] = (Cv - Sv) * wB;
        }
    }
  }
}

// ---------------- fused OLA + window + E/O split prep ----------------
__device__ inline float sample_y(const float* __restrict__ fb_,
                                 const float* __restrict__ wsinv, int j) {
  int jm = (j < PADW) ? (NFFT - j) : ((j < PADW + LOUTW) ? j : (205198 - j));
  int t1 = jm / HOPSZ; if (t1 > TT - 1) t1 = TT - 1;
  int t0 = (jm - (NFFT - HOPSZ)) / HOPSZ; if (t0 < 0) t0 = 0;
  float s = 0.f;
  for (int t = t0; t <= t1; ++t) s += fb_[t * NFFT + (jm - t * HOPSZ)];
  return s * wsinv[jm];
}

__global__ void k_olaprep(const float* __restrict__ frames, const float* __restrict__ wsinv,
                          const float* __restrict__ win,
                          _Float16* __restrict__ A2h, _Float16* __restrict__ A2l) {
  int idx = blockIdx.x * 256 + threadIdx.x;      // row*416 + n
  if (idx >= NROWS * KHALF) return;
  int row = idx / KHALF, n = idx - row * KHALF;
  size_t ab = (size_t)row * KCAT;
  if (n > 400) {                                  // K pads
    A2h[ab + n] = (_Float16)0.f; A2l[ab + n] = (_Float16)0.f;
    A2h[ab + KHALF + n] = (_Float16)0.f; A2l[ab + KHALF + n] = (_Float16)0.f;
    return;
  }
  int b = row >> 9, tt = row & 511;
  const float* fb_ = frames + (size_t)b * TT * NFFT;
  int start = tt * HOPSZ;
  float x1 = sample_y(fb_, wsinv, start + n) * win[n] * 256.0f;
  float x2 = 0.f;
  // mirror only n in [1,399]: n==400 self-maps; n==0 mirror OOB
  if (n >= 1 && n <= 399)
    x2 = sample_y(fb_, wsinv, start + 800 - n) * win[800 - n] * 256.0f;
  float E = x1 + x2, O = x1 - x2;
  _Float16 Eh = (_Float16)E;
  A2h[ab + n] = Eh;
  A2l[ab + n] = (_Float16)((E - (float)Eh) * 2048.0f);
  _Float16 Oh = (_Float16)O;
  A2h[ab + KHALF + n] = Oh;
  A2l[ab + KHALF + n] = (_Float16)((O - (float)Oh) * 2048.0f);
}

// ---------------- mm2: rfft (Re/Im symmetric) + momentum + normalize + A1' -------
__global__ __launch_bounds__(256, 2) void k_mm2(
    const _Float16* __restrict__ Ah, const _Float16* __restrict__ Al,
    const _Float16* __restrict__ Bh, const _Float16* __restrict__ Bl,
    const float* __restrict__ mag,
    float* __restrict__ tppr, float* __restrict__ tppi,
    _Float16* __restrict__ A1h, _Float16* __restrict__ A1l, float beta) {
  __shared__ __align__(16) _Float16 As_h[2][64 * 40], As_l[2][64 * 40];
  __shared__ __align__(16) _Float16 Bs_h[2][64 * 40], Bs_l[2][64 * 40];
  const int t = threadIdx.x;
  const int row0 = blockIdx.y * 64;
  const int col0 = blockIdx.x * 64;
  const int sr = t >> 2, sk = (t & 3) * 8;
  const int lane = t & 63, wv = t >> 6;
  const int wm = wv & 1, wn = wv >> 1;
  const int lm = lane & 15, qd = lane >> 4;
  f32x4 ac0[2][2] = {}, ac1[2][2] = {}, as0[2][2] = {}, as1[2][2] = {};
  const size_t abase = (size_t)(row0 + sr) * KCAT + sk;
  const size_t bbase = (size_t)(col0 + sr) * KCAT + sk;
  GEMM_LOOP
#pragma unroll
  for (int j = 0; j < 2; ++j) {
    int col = col0 + wn * 32 + j * 16 + lm;
    if (col <= 400) {
#pragma unroll
      for (int i = 0; i < 2; ++i)
#pragma unroll
        for (int r = 0; r < 4; ++r) {
          int row = row0 + wm * 32 + i * 16 + qd * 4 + r;
          int idx = row * NFREQ + col;
          float rr = ac0[i][j][r] + ac1[i][j][r] * LO_INV;   // Re (x256 scale)
          float ri = as0[i][j][r] + as1[i][j][r] * LO_INV;   // Im
          float nr = rr - beta * tppr[idx];
          float ni = ri - beta * tppi[idx];
          tppr[idx] = rr; tppi[idx] = ri;
          float den = sqrtf(nr * nr + ni * ni) + 1e-16f;
          float arv = nr / den, aiv = ni / den;
          float mg = mag[idx] * 256.0f;
          size_t ab = (size_t)row * KCAT;
          float v1 = mg * arv;
          _Float16 h1 = (_Float16)v1;
          A1h[ab + col] = h1;
          A1l[ab + col] = (_Float16)((v1 - (float)h1) * 2048.0f);
          float v2 = mg * aiv;
          _Float16 h2 = (_Float16)v2;
          A1h[ab + KHALF + col] = h2;
          A1l[ab + KHALF + col] = (_Float16)((v2 - (float)h2) * 2048.0f);
        }
    }
  }
}

// ---------------- final overlap-add (full y, once; exact divide) ----------------
__global__ void k_ola(const float* __restrict__ frames, const float* __restrict__ wsqs,
                      float* __restrict__ y) {
  int idx = blockIdx.x * blockDim.x + threadIdx.x;
  if (idx >= NB * LY) return;
  int b = idx / LY, j = idx - b * LY;
  int t1 = j / HOPSZ; if (t1 > TT - 1) t1 = TT - 1;
  int t0 = (j - (NFFT - HOPSZ)) / HOPSZ; if (t0 < 0) t0 = 0;
  const float* fb_ = frames + (size_t)b * TT * NFFT;
  float s = 0.f;
  for (int t = t0; t <= t1; ++t) s += fb_[t * NFFT + (j - t * HOPSZ)];
  y[idx] = s / wsqs[j];
}

// ---------------- epilogue: peak-normalize ----------------
__global__ void k_absmax(const float* __restrict__ y, float* __restrict__ peak) {
  __shared__ float red[256];
  int b = blockIdx.x;
  const float* yb = y + (size_t)b * LY + PADW;
  float mx = 0.f;
  for (int j = threadIdx.x; j < LOUTW; j += 256) mx = fmaxf(mx, fabsf(yb[j]));
  red[threadIdx.x] = mx;
  __syncthreads();
  for (int s2 = 128; s2 > 0; s2 >>= 1) {
    if (threadIdx.x < s2) red[threadIdx.x] = fmaxf(red[threadIdx.x], red[threadIdx.x + s2]);
    __syncthreads();
  }
  if (threadIdx.x == 0) peak[b] = red[0];
}

__global__ void k_scale(const float* __restrict__ y, const float* __restrict__ peak,
                        float* __restrict__ out, float target) {
  int idx = blockIdx.x * blockDim.x + threadIdx.x;
  if (idx >= NB * LOUTW) return;
  int b = idx / LOUTW, j = idx - b * LOUTW;
  out[idx] = y[(size_t)b * LY + PADW + j] * (target / peak[b]);
}

// ---------------- host ----------------
extern "C" void kernel_launch(void* const* d_in, const int* in_sizes, int n_in,
                              void* d_out, int out_size, void* d_ws, size_t ws_size,
                              hipStream_t stream) {
  const float* xmel = (const float*)d_in[0];   // (8, 80, 512) f32
  float* out = (float*)d_out;                  // (8, 1, 102200) f32

  char* p = (char*)d_ws;
  auto alloc = [&](size_t nbytes) -> void* {
    void* r = (void*)p;
    p += (nbytes + 255) & ~(size_t)255;
    return r;
  };
  float* mag  = (float*)alloc((size_t)NSPEC * 4);
  float* ar   = (float*)alloc((size_t)NSPEC * 4);
  float* ai   = (float*)alloc((size_t)NSPEC * 4);
  float* tpr  = (float*)alloc((size_t)NSPEC * 4);
  float* tpi  = (float*)alloc((size_t)NSPEC * 4);
  float* y    = (float*)alloc((size_t)NB * LY * 4);
  float* win  = (float*)alloc(NFFT * 4);
  float* wsqs = (float*)alloc((size_t)LY * 4);
  float* wsinv= (float*)alloc((size_t)LY * 4);
  double* ctab= (double*)alloc(NFFT * 8);
  double* stab= (double*)alloc(NFFT * 8);
  float* fbT  = (float*)alloc((size_t)NMELS * NFREQ * 4);
  float* fw0  = (float*)alloc(NFREQ * 4);
  float* fw1  = (float*)alloc(NFREQ * 4);
  float* peak = (float*)alloc(NB * 4);
  int* fm0    = (int*)alloc(NFREQ * 4);
  int* mlo    = (int*)alloc(NMELS * 4);
  int* mhi    = (int*)alloc(NMELS * 4);
  float* frames = (float*)alloc((size_t)NROWS * NFFT * 4);
  float* spec0 = frames;  // alias: consumed by k_sgd before frames written
  _Float16* A1h = (_Float16*)alloc((size_t)NROWS * KCAT * 2);
  _Float16* A1l = (_Float16*)alloc((size_t)NROWS * KCAT * 2);
  _Float16* A2h = (_Float16*)alloc((size_t)NROWS * KCAT * 2);
  _Float16* A2l = (_Float16*)alloc((size_t)NROWS * KCAT * 2);
  _Float16* B1h = (_Float16*)alloc((size_t)NCOLS * KCAT * 2);
  _Float16* B1l = (_Float16*)alloc((size_t)NCOLS * KCAT * 2);
  _Float16* B2h = (_Float16*)alloc((size_t)NCOLS * KCAT * 2);
  _Float16* B2l = (_Float16*)alloc((size_t)NCOLS * KCAT * 2);

  if ((size_t)(p - (char*)d_ws) > ws_size) return;  // insufficient scratch

  // derived threefry keys (jax partitionable split)
  unsigned k1a, k1b, k2a, k2b, kra, krb, kia, kib;
  {
    unsigned o0, o1;
    tf2x32(0u, 1u, 0u, 0u, o0, o1); k1a = o0; k1b = o1;
    tf2x32(0u, 1u, 0u, 1u, o0, o1); k2a = o0; k2b = o1;
    tf2x32(k2a, k2b, 0u, 0u, o0, o1); kra = o0; krb = o1;
    tf2x32(k2a, k2b, 0u, 1u, o0, o1); kia = o0; kib = o1;
  }

  // init: 4 consolidated kernels
  k_initA<<<(NFFT + 255) / 256, 256, 0, stream>>>(ctab, stab, fbT, fm0, fw0, fw1);
  k_ranges<<<1, 128, 0, stream>>>(fbT, mlo, mhi);
  k_initB<<<(LY + 2 * TABN + 255) / 256, 256, 0, stream>>>(
      ctab, stab, wsqs, wsinv, win, B1h, B1l, B2h, B2l);
  k_initC<<<(NSPEC + 255) / 256, 256, 0, stream>>>(
      k1a, k1b, kra, krb, kia, kib, spec0, ar, ai, tpr, tpi);

  // InverseMelScale (2 rows per 128-thread block)
  k_sgd<<<NROWS / 2, 128, 0, stream>>>(spec0, xmel, fbT, mlo, mhi, fm0, fw0, fw1, mag);

  // iteration-0 A1 (layout [Re@0|Im@416], pads zeroed once)
  k_prep1<<<dim3(4, NROWS), 256, 0, stream>>>(mag, ar, ai, A1h, A1l);

  // Griffin-Lim: 3 dispatches per iteration
  const float beta = (float)(0.99 / 1.99);
  for (int it = 0; it < GLITERS; ++it) {
    k_mm1<<<dim3(7, 64), 256, 0, stream>>>(A1h, A1l, B1h, B1l, win, frames);
    k_olaprep<<<(NROWS * KHALF + 255) / 256, 256, 0, stream>>>(frames, wsinv, win, A2h, A2l);
    k_mm2<<<dim3(7, 64), 256, 0, stream>>>(A2h, A2l, B2h, B2l,
                                           mag, tpr, tpi, A1h, A1l, beta);
  }
  // final istft with final angles (A1 written by last k_mm2)
  k_mm1<<<dim3(7, 64), 256, 0, stream>>>(A1h, A1l, B1h, B1l, win, frames);
  k_ola<<<(NB * LY + 255) / 256, 256, 0, stream>>>(frames, wsqs, y);

  // normalize
  k_absmax<<<NB, 256, 0, stream>>>(y, peak);
  const float target = (float)pow(10.0, -0.1 / 20.0);
  k_scale<<<(NB * LOUTW + 255) / 256, 256, 0, stream>>>(y, peak, out, target);
}